// Round 1
// baseline (15203.925 us; speedup 1.0000x reference)
//
#include <hip/hip_runtime.h>
#include <math.h>

#define H   64
#define L   6
#define TE  32
#define SEL 64
#define CD  128
#define DC  128
#define KK  16
#define BB  32
#define NN  8192
#define EPSV 1e-6f

__device__ __forceinline__ float swish_f(float v) {
    return v / (1.0f + __expf(-v));
}

// ---------------------------------------------------------------------------
// Kernel 1: per-(batch, object) setup. 512 blocks x 128 threads.
// Computes object_features[b,k,0:64] and the folded scale/shift table
//   tab[b,k,l,j] = cond_objects[b,k,:] @ W_ss[l,:,j] + b_ss[l,j]
// (b_ss folds in because softmax weights sum to 1).
// ---------------------------------------------------------------------------
__global__ void setup_kernel(const float* __restrict__ c, const float* __restrict__ t,
                             const float* __restrict__ W_of, const float* __restrict__ b_of,
                             const float* __restrict__ W_c1, const float* __restrict__ b_c1,
                             const float* __restrict__ W_c2, const float* __restrict__ b_c2,
                             const float* __restrict__ W_ss, const float* __restrict__ b_ss,
                             float* __restrict__ objf, float* __restrict__ tab) {
    const int bk = blockIdx.x;          // 0..511
    const int b  = bk >> 4;
    const int k  = bk & 15;
    const int tid = threadIdx.x;        // 0..127

    __shared__ float cwt[TE + DC];
    __shared__ float c1s[CD];
    __shared__ float c2s[CD];

    if (tid < 16) {
        // freqs = exp(-ln(10000) * i / 15), args = t * freqs
        float f   = __expf(-logf(10000.0f) * (float)tid * (1.0f / 15.0f));
        float arg = t[b] * f;
        cwt[tid]      = sinf(arg);
        cwt[tid + 16] = cosf(arg);
    }
    cwt[TE + tid] = c[(b * KK + k) * DC + tid];
    __syncthreads();

    // object_features = swish(cwt @ W_of + b_of)   (SEL = 64 outputs)
    if (tid < SEL) {
        float a = b_of[tid];
        for (int d = 0; d < TE + DC; ++d) a += cwt[d] * W_of[d * SEL + tid];
        objf[(b * KK + k) * SEL + tid] = swish_f(a);
    }

    // c1 = swish(cwt @ W_c1 + b_c1)   (128 outputs)
    {
        float a = b_c1[tid];
        for (int d = 0; d < TE + DC; ++d) a += cwt[d] * W_c1[d * CD + tid];
        c1s[tid] = swish_f(a);
    }
    __syncthreads();

    // c2 = swish(c1 @ W_c2 + b_c2)
    {
        float a = b_c2[tid];
        for (int d = 0; d < CD; ++d) a += c1s[d] * W_c2[d * CD + tid];
        c2s[tid] = swish_f(a);
    }
    __syncthreads();

    // tab[l][tid] = c2 @ W_ss[l,:,tid] + b_ss[l,tid]
    for (int l = 0; l < L; ++l) {
        const float* W = W_ss + l * CD * (2 * H);
        float a = b_ss[l * (2 * H) + tid];
        for (int d = 0; d < CD; ++d) a += c2s[d] * W[d * (2 * H) + tid];
        tab[((b * KK + k) * L + l) * (2 * H) + tid] = a;
    }
}

// ---------------------------------------------------------------------------
// Kernel 2: one thread per point. Block = 256 threads, 32 blocks per batch
// so `b` is wave-uniform -> all weight/table reads become scalar loads.
// ---------------------------------------------------------------------------
__global__ __launch_bounds__(256) void main_kernel(
    const float* __restrict__ x,
    const float* __restrict__ W_emb, const float* __restrict__ b_emb,
    const float* __restrict__ W_pf,  const float* __restrict__ b_pf,
    const float* __restrict__ W_h,   const float* __restrict__ b_h,
    const float* __restrict__ ln_g,  const float* __restrict__ ln_b,
    const float* __restrict__ W_out, const float* __restrict__ b_out,
    const float* __restrict__ objf,  const float* __restrict__ tab,
    float* __restrict__ out) {

    const int b  = blockIdx.x >> 5;                       // 32 blocks / batch
    const int n  = ((blockIdx.x & 31) << 8) + threadIdx.x;
    const int pt = b * NN + n;

    const float x0 = x[pt * 3 + 0];
    const float x1 = x[pt * 3 + 1];
    const float x2 = x[pt * 3 + 2];

    // x_embed (64)
    float e[H];
#pragma unroll
    for (int j = 0; j < H; ++j)
        e[j] = b_emb[j] + x0 * W_emb[j] + x1 * W_emb[H + j] + x2 * W_emb[2 * H + j];

    // affinity[k] = swish(e @ W_pf + b_pf) . objf[b,k,:]
    float aff[KK];
#pragma unroll
    for (int k = 0; k < KK; ++k) aff[k] = 0.0f;
    const float* of = objf + b * KK * SEL;
#pragma unroll
    for (int j = 0; j < H; ++j) {
        float a = b_pf[j];
#pragma unroll
        for (int i = 0; i < H; ++i) a += e[i] * W_pf[i * SEL + j];
        const float pfj = swish_f(a);
#pragma unroll
        for (int k = 0; k < KK; ++k) aff[k] += pfj * of[k * SEL + j];
    }

    // softmax over K=16
    float m = aff[0];
#pragma unroll
    for (int k = 1; k < KK; ++k) m = fmaxf(m, aff[k]);
    float sw[KK];
    float ssum = 0.0f;
#pragma unroll
    for (int k = 0; k < KK; ++k) { sw[k] = __expf(aff[k] - m); ssum += sw[k]; }
    const float inv = 1.0f / ssum;
#pragma unroll
    for (int k = 0; k < KK; ++k) sw[k] *= inv;

    // h = swish(x_embed)
    float h[H];
#pragma unroll
    for (int j = 0; j < H; ++j) h[j] = swish_f(e[j]);

    const float* tb = tab + b * KK * L * (2 * H);

    for (int l = 0; l < L; ++l) {
        const float* W  = W_h + l * H * H;
        const float* bh = b_h + l * H;

        float hn[H];
        float mu = 0.0f;
#pragma unroll
        for (int j = 0; j < H; ++j) {
            float a = bh[j];
#pragma unroll
            for (int i = 0; i < H; ++i) a += h[i] * W[i * H + j];
            a = swish_f(a);
            hn[j] = a;
            mu += a;
        }
        mu *= (1.0f / H);
        float var = 0.0f;
#pragma unroll
        for (int j = 0; j < H; ++j) { float d = hn[j] - mu; var += d * d; }
        var *= (1.0f / H);
        const float r = rsqrtf(var + EPSV);

        const float* g  = ln_g + l * H;
        const float* bl = ln_b + l * H;
#pragma unroll
        for (int j = 0; j < H; ++j) {
            const float lnv = (hn[j] - mu) * r * g[j] + bl[j];
            float sc = 0.0f, sh = 0.0f;
#pragma unroll
            for (int k = 0; k < KK; ++k) {
                const float* tk = tb + (k * L + l) * (2 * H);
                sc += sw[k] * tk[j];
                sh += sw[k] * tk[H + j];
            }
            h[j] = lnv * (1.0f + sc) + sh;
        }
    }

    // dx = h @ W_out + b_out   (64 -> 3)
    float o0 = b_out[0], o1 = b_out[1], o2 = b_out[2];
#pragma unroll
    for (int j = 0; j < H; ++j) {
        o0 += h[j] * W_out[j * 3 + 0];
        o1 += h[j] * W_out[j * 3 + 1];
        o2 += h[j] * W_out[j * 3 + 2];
    }
    out[pt * 3 + 0] = o0;
    out[pt * 3 + 1] = o1;
    out[pt * 3 + 2] = o2;
}

extern "C" void kernel_launch(void* const* d_in, const int* in_sizes, int n_in,
                              void* d_out, int out_size, void* d_ws, size_t ws_size,
                              hipStream_t stream) {
    const float* x     = (const float*)d_in[0];
    const float* c     = (const float*)d_in[1];
    const float* t     = (const float*)d_in[2];
    const float* W_emb = (const float*)d_in[3];
    const float* b_emb = (const float*)d_in[4];
    const float* W_pf  = (const float*)d_in[5];
    const float* b_pf  = (const float*)d_in[6];
    const float* W_of  = (const float*)d_in[7];
    const float* b_of  = (const float*)d_in[8];
    const float* W_c1  = (const float*)d_in[9];
    const float* b_c1  = (const float*)d_in[10];
    const float* W_c2  = (const float*)d_in[11];
    const float* b_c2  = (const float*)d_in[12];
    const float* W_h   = (const float*)d_in[13];
    const float* b_h   = (const float*)d_in[14];
    const float* W_ss  = (const float*)d_in[15];
    const float* b_ss  = (const float*)d_in[16];
    const float* ln_g  = (const float*)d_in[17];
    const float* ln_b  = (const float*)d_in[18];
    const float* W_out = (const float*)d_in[19];
    const float* b_out = (const float*)d_in[20];
    float* out = (float*)d_out;

    float* objf = (float*)d_ws;                       // B*K*SEL      = 32768 f32
    float* tab  = objf + BB * KK * SEL;               // B*K*L*2H     = 393216 f32

    setup_kernel<<<BB * KK, 128, 0, stream>>>(c, t, W_of, b_of, W_c1, b_c1,
                                              W_c2, b_c2, W_ss, b_ss, objf, tab);
    main_kernel<<<(BB * NN) / 256, 256, 0, stream>>>(x, W_emb, b_emb, W_pf, b_pf,
                                                     W_h, b_h, ln_g, ln_b,
                                                     W_out, b_out, objf, tab, out);
}

// Round 2
// 157.708 us; speedup vs baseline: 96.4054x; 96.4054x over previous
//
#include <hip/hip_runtime.h>
#include <hip/hip_bf16.h>
#include <math.h>

#define H   64
#define L   6
#define TE  32
#define SEL 64
#define CD  128
#define DC  128
#define KK  16
#define BB  32
#define NN  8192
#define EPSV 1e-6f

typedef float f32x4 __attribute__((ext_vector_type(4)));
typedef short bf16x8 __attribute__((ext_vector_type(8)));

__device__ __forceinline__ float swish_f(float v) { return v / (1.0f + __expf(-v)); }
__device__ __forceinline__ short f2bf(float f) {
    __hip_bfloat16 h = __float2bfloat16(f);
    return *reinterpret_cast<short*>(&h);
}

// ws layout (shorts): objffrag[32][2][64][8] | tabfrag[32][6][8][64][8] |
//                     whfrag[6][4][2][64][8] | wpffrag[4][2][64][8]
#define OFF_OBJF 0
#define OFF_TAB  32768
#define OFF_WH   819200
#define OFF_WPF  843776

// ---------------------------------------------------------------------------
// Weight fragments: A-frag layout = A[row=16t+(lane&15)][k=32s+8*(lane>>4)+jj]
// For matvec C = W^T h : A[j][i] = W[i][j]  ->  frag = W[k][row].
// Also zero-fills tabfrag lanes 32..63 (K=16 padded to 32).
// ---------------------------------------------------------------------------
__global__ void setup_w(const float* __restrict__ W_h, const float* __restrict__ W_pf,
                        short* __restrict__ whfrag, short* __restrict__ wpffrag,
                        short* __restrict__ tabfrag) {
    const int gid = blockIdx.x * 256 + threadIdx.x;     // 64 blocks -> 16384 threads
    for (int idx = gid; idx < 6 * 4 * 2 * 64 * 8; idx += 16384) {
        const int jj = idx & 7, lane = (idx >> 3) & 63, s = (idx >> 9) & 1,
                  t = (idx >> 10) & 3, l = idx >> 12;
        const int g = lane >> 4, row = 16 * t + (lane & 15), k = 32 * s + 8 * g + jj;
        whfrag[idx] = f2bf(W_h[(l * H + k) * H + row]);
    }
    for (int idx = gid; idx < 4 * 2 * 64 * 8; idx += 16384) {
        const int jj = idx & 7, lane = (idx >> 3) & 63, s = (idx >> 9) & 1, t = idx >> 10;
        const int g = lane >> 4, row = 16 * t + (lane & 15), k = 32 * s + 8 * g + jj;
        wpffrag[idx] = f2bf(W_pf[k * SEL + row]);
    }
    for (int idx = gid; idx < 32 * 6 * 8 * 32 * 8; idx += 16384) {
        const int jj = idx & 7, lane32 = (idx >> 3) & 31, t = (idx >> 8) & 7, bl = idx >> 11;
        tabfrag[((bl * 8 + t) * 64 + 32 + lane32) * 8 + jj] = 0;
    }
}

// ---------------------------------------------------------------------------
// Per-(b,k) object setup: objf A-frag (affinity) + folded scale/shift table
// A-frag (tab^T): row = j-dim, k = object index (valid k<16 -> lanes 0..31).
// ---------------------------------------------------------------------------
__global__ void setup_obj(const float* __restrict__ c, const float* __restrict__ t,
                          const float* __restrict__ W_of, const float* __restrict__ b_of,
                          const float* __restrict__ W_c1, const float* __restrict__ b_c1,
                          const float* __restrict__ W_c2, const float* __restrict__ b_c2,
                          const float* __restrict__ W_ss, const float* __restrict__ b_ss,
                          short* __restrict__ objffrag, short* __restrict__ tabfrag) {
    const int bk = blockIdx.x, b = bk >> 4, k = bk & 15;
    const int tid = threadIdx.x;                        // 0..127
    __shared__ float cwt[TE + DC];
    __shared__ float c1s[CD], c2s[CD];

    if (tid < 16) {
        float f   = __expf(-logf(10000.0f) * (float)tid * (1.0f / 15.0f));
        float arg = t[b] * f;
        cwt[tid]      = sinf(arg);
        cwt[tid + 16] = cosf(arg);
    }
    cwt[TE + tid] = c[(b * KK + k) * DC + tid];
    __syncthreads();

    if (tid < SEL) {   // object_features -> A-frag for affinity (A[row=k][kdim=tid])
        float a = b_of[tid];
        for (int d = 0; d < TE + DC; ++d) a += cwt[d] * W_of[d * SEL + tid];
        a = swish_f(a);
        const int s = tid >> 5, g = (tid >> 3) & 3, jj = tid & 7;
        objffrag[(((b * 2 + s) * 64) + (16 * g + k)) * 8 + jj] = f2bf(a);
    }
    {
        float a = b_c1[tid];
        for (int d = 0; d < TE + DC; ++d) a += cwt[d] * W_c1[d * CD + tid];
        c1s[tid] = swish_f(a);
    }
    __syncthreads();
    {
        float a = b_c2[tid];
        for (int d = 0; d < CD; ++d) a += c1s[d] * W_c2[d * CD + tid];
        c2s[tid] = swish_f(a);
    }
    __syncthreads();

    // tab[l][j=tid] = c2 @ W_ss[l,:,j] + b_ss[l,j]; A-frag: row=j, kdim=k
    const int tt = tid >> 4, pp = tid & 15, lane = 16 * (k >> 3) + pp, jj = k & 7;
    for (int l = 0; l < L; ++l) {
        const float* W = W_ss + l * CD * (2 * H);
        float a = b_ss[l * (2 * H) + tid];
        for (int d = 0; d < CD; ++d) a += c2s[d] * W[d * (2 * H) + tid];
        tabfrag[((((b * 6 + l) * 8 + tt) * 64) + lane) * 8 + jj] = f2bf(a);
    }
}

// ---------------------------------------------------------------------------
// Main: 1024 blocks x 256 threads (4 waves). Block = 1 batch-chunk of 256 pts.
// Wave handles 4 tiles of 16 points. All MFMA in swapped form:
//   C[row=outdim][col=point], lane: col=lane&15, row=(lane>>4)*4+reg (+16*tile)
//   A-frag: row=lane&15(+16t), k=8*(lane>>4)+jj(+32s); B-frag: col=lane&15, same k
// ---------------------------------------------------------------------------
__global__ __launch_bounds__(256, 2) void main_kernel(
    const float* __restrict__ x,
    const float* __restrict__ W_emb, const float* __restrict__ b_emb,
    const float* __restrict__ b_pf,  const float* __restrict__ b_h,
    const float* __restrict__ ln_g,  const float* __restrict__ ln_b,
    const float* __restrict__ W_out, const float* __restrict__ b_out,
    const short* __restrict__ objffrag, const short* __restrict__ tabfrag,
    const short* __restrict__ whfrag,   const short* __restrict__ wpffrag,
    float* __restrict__ out) {

    __shared__ short hlds[256 * 72];        // [point][dim], stride 72 (144B, 16B-aligned)
    __shared__ short afrag[16 * 64 * 8];    // per-layer staged A-frags: 8 wh + 8 tab units

    const int tid  = threadIdx.x;
    const int wave = tid >> 6, lane = tid & 63;
    const int p = lane & 15, g = lane >> 4;
    const int b = blockIdx.x >> 5;
    const int point0 = (blockIdx.x & 31) << 8;

    // wave-hoisted fragments (phase A only)
    bf16x8 wpfr[4][2], objr[2];
#pragma unroll
    for (int t = 0; t < 4; ++t)
#pragma unroll
        for (int s = 0; s < 2; ++s)
            wpfr[t][s] = *(const bf16x8*)&wpffrag[(((t * 2 + s) * 64) + lane) * 8];
#pragma unroll
    for (int s = 0; s < 2; ++s)
        objr[s] = *(const bf16x8*)&objffrag[(((b * 2 + s) * 64) + lane) * 8];

    bf16x8 swfrag[4];

    // ---------------- Phase A: embed, pf, affinity, softmax, h0 ----------------
#pragma unroll
    for (int i = 0; i < 4; ++i) {
        const int tloc = (wave * 4 + i) * 16 + p;
        const int ptg  = b * NN + point0 + tloc;
        const float x0 = x[ptg * 3 + 0], x1 = x[ptg * 3 + 1], x2 = x[ptg * 3 + 2];

        float  ev[2][8];
        bf16x8 eb[2];
#pragma unroll
        for (int s = 0; s < 2; ++s)
#pragma unroll
            for (int jj = 0; jj < 8; ++jj) {
                const int k = 32 * s + 8 * g + jj;
                float e = b_emb[k] + x0 * W_emb[k] + x1 * W_emb[H + k] + x2 * W_emb[2 * H + k];
                ev[s][jj] = e;
                eb[s][jj] = f2bf(e);
            }

        // pf matvec: C = W_pf^T e
        f32x4 macc[4];
#pragma unroll
        for (int t = 0; t < 4; ++t) {
            f32x4 z = {0.f, 0.f, 0.f, 0.f};
            macc[t] = z;
#pragma unroll
            for (int s = 0; s < 2; ++s)
                macc[t] = __builtin_amdgcn_mfma_f32_16x16x32_bf16(wpfr[t][s], eb[s], macc[t], 0, 0, 0);
        }
        // pf = swish(. + b_pf), write C-layout to LDS
#pragma unroll
        for (int t = 0; t < 4; ++t) {
            const float4 bp = *(const float4*)&b_pf[16 * t + 4 * g];
            float bpv[4]; bpv[0] = bp.x; bpv[1] = bp.y; bpv[2] = bp.z; bpv[3] = bp.w;
            short4 w;
            w.x = f2bf(swish_f(macc[t][0] + bpv[0]));
            w.y = f2bf(swish_f(macc[t][1] + bpv[1]));
            w.z = f2bf(swish_f(macc[t][2] + bpv[2]));
            w.w = f2bf(swish_f(macc[t][3] + bpv[3]));
            *(short4*)&hlds[tloc * 72 + 16 * t + 4 * g] = w;
        }
        // read pf B-frags (same-wave LDS RAW is in-order)
        bf16x8 pfb[2];
#pragma unroll
        for (int s = 0; s < 2; ++s)
            pfb[s] = *(bf16x8*)&hlds[tloc * 72 + 32 * s + 8 * g];

        // affinity: C[obj][point]
        f32x4 aacc = {0.f, 0.f, 0.f, 0.f};
#pragma unroll
        for (int s = 0; s < 2; ++s)
            aacc = __builtin_amdgcn_mfma_f32_16x16x32_bf16(objr[s], pfb[s], aacc, 0, 0, 0);

        // softmax over 16 objects (4 per lane x 4 g-groups)
        float mx = fmaxf(fmaxf(aacc[0], aacc[1]), fmaxf(aacc[2], aacc[3]));
        mx = fmaxf(mx, __shfl_xor(mx, 16));
        mx = fmaxf(mx, __shfl_xor(mx, 32));
        float swv[4], ss = 0.f;
#pragma unroll
        for (int r = 0; r < 4; ++r) { swv[r] = __expf(aacc[r] - mx); ss += swv[r]; }
        ss += __shfl_xor(ss, 16);
        ss += __shfl_xor(ss, 32);
        const float inv = 1.0f / ss;
#pragma unroll
        for (int r = 0; r < 4; ++r) swv[r] *= inv;

        // redistribute to B-frag: lane needs sw[k], k=8g+jj (k<16 valid)
        bf16x8 sf;
#pragma unroll
        for (int jj = 0; jj < 8; ++jj) {
            const int k = 8 * g + jj;
            const float v = __shfl(swv[jj & 3], p + 16 * ((k >> 2) & 3));
            sf[jj] = (g < 2) ? f2bf(v) : (short)0;
        }
        swfrag[i] = sf;

        // h0 = swish(x_embed), already in B-frag positions
#pragma unroll
        for (int s = 0; s < 2; ++s) {
            bf16x8 hb;
#pragma unroll
            for (int jj = 0; jj < 8; ++jj) hb[jj] = f2bf(swish_f(ev[s][jj]));
            *(bf16x8*)&hlds[tloc * 72 + 32 * s + 8 * g] = hb;
        }
    }

    // ---------------- AdaLN layers ----------------
    for (int l = 0; l < L; ++l) {
        __syncthreads();
        {   // stage this layer's wh (8KB) + tab (8KB) A-frags into LDS
            const int* srcw = (const int*)(whfrag + l * 4096);
            const int* srct = (const int*)(tabfrag + (b * 6 + l) * 4096);
            int* dst = (int*)afrag;
#pragma unroll
            for (int u = 0; u < 8; ++u) {
                dst[u * 256 + tid]        = srcw[u * 256 + tid];
                dst[2048 + u * 256 + tid] = srct[u * 256 + tid];
            }
        }
        __syncthreads();

        bf16x8 whr[4][2], tabr[8];
#pragma unroll
        for (int t = 0; t < 4; ++t)
#pragma unroll
            for (int s = 0; s < 2; ++s)
                whr[t][s] = *(bf16x8*)&afrag[((t * 2 + s) * 64 + lane) * 8];
#pragma unroll
        for (int u = 0; u < 8; ++u)
            tabr[u] = *(bf16x8*)&afrag[((8 + u) * 64 + lane) * 8];

#pragma unroll
        for (int i = 0; i < 4; ++i) {
            const int tloc = (wave * 4 + i) * 16 + p;
            const bf16x8 hb0 = *(bf16x8*)&hlds[tloc * 72 + 8 * g];
            const bf16x8 hb1 = *(bf16x8*)&hlds[tloc * 72 + 32 + 8 * g];

            f32x4 macc[4];
#pragma unroll
            for (int t = 0; t < 4; ++t) {
                f32x4 z = {0.f, 0.f, 0.f, 0.f};
                macc[t] = __builtin_amdgcn_mfma_f32_16x16x32_bf16(whr[t][0], hb0, z, 0, 0, 0);
                macc[t] = __builtin_amdgcn_mfma_f32_16x16x32_bf16(whr[t][1], hb1, macc[t], 0, 0, 0);
            }
            f32x4 sacc[8];
#pragma unroll
            for (int u = 0; u < 8; ++u) {
                f32x4 z = {0.f, 0.f, 0.f, 0.f};
                sacc[u] = __builtin_amdgcn_mfma_f32_16x16x32_bf16(tabr[u], swfrag[i], z, 0, 0, 0);
            }

            // swish(matvec + b_h), LN stats
            float hn[4][4], s1 = 0.f, s2 = 0.f;
#pragma unroll
            for (int t = 0; t < 4; ++t) {
                const float4 bh = *(const float4*)&b_h[l * H + 16 * t + 4 * g];
                float bhv[4]; bhv[0] = bh.x; bhv[1] = bh.y; bhv[2] = bh.z; bhv[3] = bh.w;
#pragma unroll
                for (int r = 0; r < 4; ++r) {
                    const float v = swish_f(macc[t][r] + bhv[r]);
                    hn[t][r] = v; s1 += v; s2 += v * v;
                }
            }
            s1 += __shfl_xor(s1, 16); s1 += __shfl_xor(s1, 32);
            s2 += __shfl_xor(s2, 16); s2 += __shfl_xor(s2, 32);
            const float mu  = s1 * (1.0f / 64.0f);
            const float var = s2 * (1.0f / 64.0f) - mu * mu;
            const float rin = rsqrtf(var + EPSV);

            if (l < L - 1) {
#pragma unroll
                for (int t = 0; t < 4; ++t) {
                    const float4 gg = *(const float4*)&ln_g[l * H + 16 * t + 4 * g];
                    const float4 bb = *(const float4*)&ln_b[l * H + 16 * t + 4 * g];
                    float ggv[4]; ggv[0] = gg.x; ggv[1] = gg.y; ggv[2] = gg.z; ggv[3] = gg.w;
                    float bbv[4]; bbv[0] = bb.x; bbv[1] = bb.y; bbv[2] = bb.z; bbv[3] = bb.w;
                    short4 w;
                    float lnv, hv;
                    lnv = (hn[t][0] - mu) * rin * ggv[0] + bbv[0];
                    hv  = lnv * (1.0f + sacc[t][0]) + sacc[4 + t][0]; w.x = f2bf(hv);
                    lnv = (hn[t][1] - mu) * rin * ggv[1] + bbv[1];
                    hv  = lnv * (1.0f + sacc[t][1]) + sacc[4 + t][1]; w.y = f2bf(hv);
                    lnv = (hn[t][2] - mu) * rin * ggv[2] + bbv[2];
                    hv  = lnv * (1.0f + sacc[t][2]) + sacc[4 + t][2]; w.z = f2bf(hv);
                    lnv = (hn[t][3] - mu) * rin * ggv[3] + bbv[3];
                    hv  = lnv * (1.0f + sacc[t][3]) + sacc[4 + t][3]; w.w = f2bf(hv);
                    *(short4*)&hlds[tloc * 72 + 16 * t + 4 * g] = w;
                }
            } else {
                float d0 = 0.f, d1 = 0.f, d2 = 0.f;
#pragma unroll
                for (int t = 0; t < 4; ++t) {
                    const float4 gg = *(const float4*)&ln_g[l * H + 16 * t + 4 * g];
                    const float4 bb = *(const float4*)&ln_b[l * H + 16 * t + 4 * g];
                    float ggv[4]; ggv[0] = gg.x; ggv[1] = gg.y; ggv[2] = gg.z; ggv[3] = gg.w;
                    float bbv[4]; bbv[0] = bb.x; bbv[1] = bb.y; bbv[2] = bb.z; bbv[3] = bb.w;
                    const float4 w0 = *(const float4*)&W_out[(16 * t + 4 * g) * 3];
                    const float4 w1 = *(const float4*)&W_out[(16 * t + 4 * g) * 3 + 4];
                    const float4 w2 = *(const float4*)&W_out[(16 * t + 4 * g) * 3 + 8];
                    float wv[12];
                    wv[0] = w0.x; wv[1] = w0.y; wv[2]  = w0.z; wv[3]  = w0.w;
                    wv[4] = w1.x; wv[5] = w1.y; wv[6]  = w1.z; wv[7]  = w1.w;
                    wv[8] = w2.x; wv[9] = w2.y; wv[10] = w2.z; wv[11] = w2.w;
#pragma unroll
                    for (int r = 0; r < 4; ++r) {
                        const float lnv = (hn[t][r] - mu) * rin * ggv[r] + bbv[r];
                        const float hv  = lnv * (1.0f + sacc[t][r]) + sacc[4 + t][r];
                        d0 += hv * wv[r * 3 + 0];
                        d1 += hv * wv[r * 3 + 1];
                        d2 += hv * wv[r * 3 + 2];
                    }
                }
                d0 += __shfl_xor(d0, 16); d0 += __shfl_xor(d0, 32);
                d1 += __shfl_xor(d1, 16); d1 += __shfl_xor(d1, 32);
                d2 += __shfl_xor(d2, 16); d2 += __shfl_xor(d2, 32);
                if (g == 0) {
                    const int ptg = b * NN + point0 + tloc;
                    out[ptg * 3 + 0] = d0 + b_out[0];
                    out[ptg * 3 + 1] = d1 + b_out[1];
                    out[ptg * 3 + 2] = d2 + b_out[2];
                }
            }
        }
    }
}

extern "C" void kernel_launch(void* const* d_in, const int* in_sizes, int n_in,
                              void* d_out, int out_size, void* d_ws, size_t ws_size,
                              hipStream_t stream) {
    const float* x     = (const float*)d_in[0];
    const float* c     = (const float*)d_in[1];
    const float* t     = (const float*)d_in[2];
    const float* W_emb = (const float*)d_in[3];
    const float* b_emb = (const float*)d_in[4];
    const float* W_pf  = (const float*)d_in[5];
    const float* b_pf  = (const float*)d_in[6];
    const float* W_of  = (const float*)d_in[7];
    const float* b_of  = (const float*)d_in[8];
    const float* W_c1  = (const float*)d_in[9];
    const float* b_c1  = (const float*)d_in[10];
    const float* W_c2  = (const float*)d_in[11];
    const float* b_c2  = (const float*)d_in[12];
    const float* W_h   = (const float*)d_in[13];
    const float* b_h   = (const float*)d_in[14];
    const float* W_ss  = (const float*)d_in[15];
    const float* b_ss  = (const float*)d_in[16];
    const float* ln_g  = (const float*)d_in[17];
    const float* ln_b  = (const float*)d_in[18];
    const float* W_out = (const float*)d_in[19];
    const float* b_out = (const float*)d_in[20];
    float* out = (float*)d_out;

    short* wsb      = (short*)d_ws;
    short* objffrag = wsb + OFF_OBJF;
    short* tabfrag  = wsb + OFF_TAB;
    short* whfrag   = wsb + OFF_WH;
    short* wpffrag  = wsb + OFF_WPF;

    setup_w<<<64, 256, 0, stream>>>(W_h, W_pf, whfrag, wpffrag, tabfrag);
    setup_obj<<<BB * KK, 128, 0, stream>>>(c, t, W_of, b_of, W_c1, b_c1,
                                           W_c2, b_c2, W_ss, b_ss, objffrag, tabfrag);
    main_kernel<<<1024, 256, 0, stream>>>(x, W_emb, b_emb, b_pf, b_h, ln_g, ln_b,
                                          W_out, b_out, objffrag, tabfrag,
                                          whfrag, wpffrag, out);
}